// Round 8
// baseline (12034.463 us; speedup 1.0000x reference)
//
#include <hip/hip_runtime.h>

typedef __bf16 bf16;
typedef __bf16 bf16x8 __attribute__((ext_vector_type(8)));
typedef __bf16 bf16x4 __attribute__((ext_vector_type(4)));
typedef float  f32x4  __attribute__((ext_vector_type(4)));
typedef unsigned int u32;

#define B_TOT 4096
#define T_SEQ 64
#define NT_OUT 8
#define NTHR 512
#define NBLK 256
#define GSZ  8

// ---- ws layout (bytes) ----
#define WS_W0   0           // 512x256 bf16 packed frags
#define WS_W1   262144
#define WS_W2   786432
#define WS_WHH  1048576
#define WS_WIH  1441792
#define WS_BC   1490944     // 64x768 f32
#define WS_GY   1703936     // 32 groups x 64KB   (y_stage / GRU h buf0)
#define WS_GYB  3801088     // 32 x 64KB          (GRU h buf1)
#define WS_GH1  5898240     // 32 x 128KB
#define WS_GH2  10092544    // 32 x 128KB
#define WS_FLG  14286848    // 32 groups x 128B  (fY@0, fH1@64, fH2@128 bytes... u32 idx 0/16/32)
#define WS_MAP  14290944    // 256 u32 xcd map + gctr @ +1024

// Tsit5 tableau
constexpr float A21 = 0.161f;
constexpr float A31 = -0.008480655492356989f, A32 = 0.335480655492357f;
constexpr float A41 = 2.8971530571054935f, A42 = -6.359448489975075f, A43 = 4.362295432869581f;
constexpr float A51 = 5.325864828439257f, A52 = -11.748883564062828f, A53 = 7.4955393428898365f, A54 = -0.09249506636175525f;
constexpr float A61 = 5.86145544294642f, A62 = -12.92096931784711f, A63 = 8.159367898576159f, A64 = -0.071584973281401f, A65 = -0.028269050394068383f;
constexpr float BC1 = 0.09646076681806523f, BC2 = 0.01f, BC3 = 0.4798896504144996f;
constexpr float BC4 = 1.379008574103742f, BC5 = -3.290069515436081f, BC6 = 2.324710524099774f;
constexpr float DT = 0.1f;
constexpr float BROW[5][5] = {
    {A21, 0, 0, 0, 0},
    {A31, A32, 0, 0, 0},
    {A41, A42, A43, 0, 0},
    {A51, A52, A53, A54, 0},
    {A61, A62, A63, A64, A65}};
constexpr float FCF[6] = {BC1, BC2, BC3, BC4, BC5, BC6};

__device__ __forceinline__ f32x4 MFMA(bf16x8 a, bf16x8 b, f32x4 c) {
    return __builtin_amdgcn_mfma_f32_16x16x32_bf16(a, b, c, 0, 0, 0);
}
__device__ __forceinline__ float eluf(float x) { return x > 0.f ? x : __expf(x) - 1.f; }
__device__ __forceinline__ float sigm_f(float x) { return 1.f / (1.f + __expf(-x)); }
__device__ __forceinline__ float tanh_f(float x) { return 1.f - 2.f / (__expf(2.f * x) + 1.f); }

// ---- coherent global access (FAST: group verified on one XCD -> sc0 only) ----
template<bool FAST>
__device__ __forceinline__ void ld4g(const bf16* p, bf16x8& a0, bf16x8& a1, bf16x8& a2, bf16x8& a3) {
    if constexpr (FAST) {
        asm volatile(
            "global_load_dwordx4 %0, %4, off sc0\n\t"
            "global_load_dwordx4 %1, %4, off offset:1024 sc0\n\t"
            "global_load_dwordx4 %2, %4, off offset:2048 sc0\n\t"
            "global_load_dwordx4 %3, %4, off offset:3072 sc0"
            : "=&v"(a0), "=&v"(a1), "=&v"(a2), "=&v"(a3) : "v"(p) : "memory");
    } else {
        asm volatile(
            "global_load_dwordx4 %0, %4, off sc0 sc1\n\t"
            "global_load_dwordx4 %1, %4, off offset:1024 sc0 sc1\n\t"
            "global_load_dwordx4 %2, %4, off offset:2048 sc0 sc1\n\t"
            "global_load_dwordx4 %3, %4, off offset:3072 sc0 sc1"
            : "=&v"(a0), "=&v"(a1), "=&v"(a2), "=&v"(a3) : "v"(p) : "memory");
    }
}
template<bool FAST>
__device__ __forceinline__ bf16x8 ld1g(const bf16* p) {
    bf16x8 a;
    if constexpr (FAST)
        asm volatile("global_load_dwordx4 %0, %1, off sc0\n\ts_waitcnt vmcnt(0)"
                     : "=v"(a) : "v"(p) : "memory");
    else
        asm volatile("global_load_dwordx4 %0, %1, off sc0 sc1\n\ts_waitcnt vmcnt(0)"
                     : "=v"(a) : "v"(p) : "memory");
    return a;
}
template<bool FAST>
__device__ __forceinline__ void st4g(bf16* p, bf16x4 v) {
    if constexpr (FAST) *(bf16x4*)p = v;
    else asm volatile("global_store_dwordx2 %0, %1, off sc0 sc1" :: "v"(p), "v"(v) : "memory");
}
__device__ __forceinline__ void vmwait() {
    asm volatile("s_waitcnt vmcnt(0)" ::: "memory");
    __builtin_amdgcn_sched_barrier(0);
}

// ---- block-lockstep group rendezvous (round-5 proven semantics) ----
__device__ __forceinline__ void produce(u32* f, int tid) {
    asm volatile("s_waitcnt vmcnt(0)" ::: "memory");   // own wave's stores acked
    __syncthreads();                                   // all waves drained
    if (tid == 0) __hip_atomic_fetch_add(f, 1u, __ATOMIC_RELAXED, __HIP_MEMORY_SCOPE_AGENT);
}
__device__ __forceinline__ void consume(const u32* f, u32 tgt, int tid) {
    if (tid == 0) {
        while (__hip_atomic_load(f, __ATOMIC_RELAXED, __HIP_MEMORY_SCOPE_AGENT) < tgt)
            __builtin_amdgcn_s_sleep(1);
    }
    __syncthreads();
}

// ---- GEMM core: acc[m] = W_tile(LDS) x acts^T(global), D lane=batch ----
template<int KK, int NM, bool FAST>
__device__ __forceinline__ void gemm_core(const bf16* sWl, const bf16* ginl, int MSIN,
                                          f32x4 (&acc)[NM]) {
    bf16x8 wr[KK];
    #pragma unroll
    for (int kk = 0; kk < KK; ++kk) wr[kk] = *(const bf16x8*)&sWl[kk * 512];
    #pragma unroll
    for (int m = 0; m < NM; ++m) {
        bf16x8 a[KK];
        const bf16* p = ginl + m * MSIN;
        #pragma unroll
        for (int kq = 0; kq < KK; kq += 4)
            ld4g<FAST>(p + kq * 512, a[kq], a[kq + 1], a[kq + 2], a[kq + 3]);
        vmwait();
        f32x4 e = {0.f, 0.f, 0.f, 0.f}, o = {0.f, 0.f, 0.f, 0.f};
        #pragma unroll
        for (int kk = 0; kk < KK; kk += 2) {
            e = MFMA(wr[kk], a[kk], e);
            o = MFMA(wr[kk + 1], a[kk + 1], o);
        }
        acc[m] = e + o;
    }
}

template<bool ELU, int NM, bool FAST>
__device__ __forceinline__ void store_out(bf16* dst, int MS, const float (&bias)[4],
                                          const f32x4 (&acc)[NM]) {
    #pragma unroll
    for (int m = 0; m < NM; ++m) {
        bf16x4 ov;
        #pragma unroll
        for (int r = 0; r < 4; ++r) {
            float v = acc[m][r] + bias[r];
            if constexpr (ELU) v = eluf(v);
            ov[r] = (bf16)v;
        }
        st4g<FAST>(dst + m * MS, ov);
    }
}

// ---- one Tsit5 stage: entered with gY consumed; block-lockstep rendezvous ----
template<int ST, bool FAST>
__device__ __forceinline__ void ode_stage(
    const bf16* sW0l, const bf16* sW1l, const bf16* sW2l,
    const bf16* gYl, bf16* gH1d, const bf16* gH1l, bf16* gH2d, const bf16* gH2l, bf16* gYd,
    u32* fY, u32* fH1, u32* fH2, int tid,
    const float (&b0w)[4], const float (&b1w)[4], const float (&b2w)[4],
    f32x4 (&yreg)[2], f32x4 (&kreg)[5][2],
    u32& eY, u32& eH1, u32& eH2) {
    // L0
    {
        f32x4 acc[4];
        gemm_core<8, 4, FAST>(sW0l, gYl, 4096, acc);
        store_out<true, 4, FAST>(gH1d, 8192, b0w, acc);
    }
    produce(fH1, tid); ++eH1;
    consume(fH1, GSZ * eH1, tid);
    // L1
    {
        f32x4 acc[4];
        gemm_core<16, 4, FAST>(sW1l, gH1l, 8192, acc);
        store_out<true, 4, FAST>(gH2d, 8192, b1w, acc);
    }
    produce(fH2, tid); ++eH2;
    consume(fH2, GSZ * eH2, tid);
    // L2 + Tsit5 build
    {
        f32x4 acc[2];
        gemm_core<16, 2, FAST>(sW2l, gH2l, 8192, acc);
        #pragma unroll
        for (int i = 0; i < 2; ++i) {
            f32x4 kv;
            #pragma unroll
            for (int r = 0; r < 4; ++r) kv[r] = acc[i][r] + b2w[r];
            f32x4 yst;
            if constexpr (ST < 5) {
                kreg[ST][i] = kv;
                yst = yreg[i];
                #pragma unroll
                for (int s = 0; s <= ST; ++s) {
                    const float c = DT * BROW[ST][s];
                    #pragma unroll
                    for (int r = 0; r < 4; ++r) yst[r] += c * kreg[s][i][r];
                }
            } else {
                #pragma unroll
                for (int s = 0; s < 5; ++s) {
                    const float c = DT * FCF[s];
                    #pragma unroll
                    for (int r = 0; r < 4; ++r) yreg[i][r] += c * kreg[s][i][r];
                }
                #pragma unroll
                for (int r = 0; r < 4; ++r) yreg[i][r] += (DT * FCF[5]) * kv[r];
                yst = yreg[i];
            }
            bf16x4 ov;
            #pragma unroll
            for (int r = 0; r < 4; ++r) ov[r] = (bf16)yst[r];
            st4g<FAST>(gYd + i * 4096, ov);
        }
    }
    produce(fY, tid); ++eY;
}

// ---- decode: block rank j emits its group's rows 16j..16j+15 for unit u ----
template<bool FAST>
__device__ __forceinline__ void dec_unit(const bf16* gY, const float* sWdec, const float* sBdec,
                                         float* out, int g, int j, int w, int lane, int H, int u) {
    const int rloc = 2 * w + (lane >> 5);
    const int li = lane & 31;
    const bf16* p = gY + (size_t)j * 4096 + (((li >> 2) * 64 + (li & 3) * 16 + rloc)) * 8;
    bf16x8 yv = ld1g<FAST>(p);
    const int f0 = li * 8;
    float acc[8];
    #pragma unroll
    for (int t = 0; t < 8; ++t) acc[t] = 0.f;
    #pragma unroll
    for (int e = 0; e < 8; ++e) {
        const float yf = (float)yv[e];
        #pragma unroll
        for (int t = 0; t < 8; ++t) acc[t] += yf * sWdec[t * 256 + f0 + e];
    }
    #pragma unroll
    for (int k = 1; k < 32; k <<= 1)
        #pragma unroll
        for (int t = 0; t < 8; ++t) acc[t] += __shfl_xor(acc[t], k, 64);
    if (li == 0) {
        const size_t row = (size_t)g * 128 + 16 * j + rloc;
        #pragma unroll
        for (int t = 0; t < 8; ++t) out[(row * H + u) * NT_OUT + t] = acc[t] + sBdec[t];
    }
}

template<bool FAST>
__device__ void body(const float* __restrict__ x_seq, const int* __restrict__ cidx,
                     const float* __restrict__ b_n, const float* __restrict__ b0,
                     const float* __restrict__ b1, const float* __restrict__ b2,
                     const float* __restrict__ W_dec, const float* __restrict__ b_dec,
                     char* __restrict__ ws, float* __restrict__ out, char* SM,
                     int H, int g, int j) {
    const int tid = threadIdx.x, w = tid >> 6, lane = tid & 63;
    const int lm = lane & 15, q = lane >> 4, q4 = q << 2;
    const int grow0 = g * 128;

    const bf16* W0p  = (const bf16*)(ws + WS_W0);
    const bf16* W1p  = (const bf16*)(ws + WS_W1);
    const bf16* W2p  = (const bf16*)(ws + WS_W2);
    const bf16* WhhP = (const bf16*)(ws + WS_WHH);
    const bf16* WihP = (const bf16*)(ws + WS_WIH);
    const float* bias_c = (const float*)(ws + WS_BC);
    bf16* gY  = (bf16*)(ws + WS_GY)  + (size_t)g * 32768;
    bf16* gYb = (bf16*)(ws + WS_GYB) + (size_t)g * 32768;
    bf16* gH1 = (bf16*)(ws + WS_GH1) + (size_t)g * 65536;
    bf16* gH2 = (bf16*)(ws + WS_GH2) + (size_t)g * 65536;
    u32* fl  = (u32*)(ws + WS_FLG + (size_t)g * 128);
    u32 *fY = fl, *fH1 = fl + 16, *fH2 = fl + 32;

    bf16*  sWgt  = (bf16*)SM;                    // 128KB ODE weights / 54KB GRU weights
    float* sWdec = (float*)(SM + 131072);        // 8KB
    float* yx    = (float*)(SM + 139264);        // 16KB f32 h_final transfer (also mapL region pre-GRU is below)
    float* sBdec = (float*)(SM + 155648);

    u32 eY = 0, eH1 = 0, eH2 = 0;

    // ---- stage decode weights + GRU weight slices into LDS ----
    for (int i = tid; i < 2048; i += NTHR) sWdec[i] = W_dec[i];
    if (tid < 8) sBdec[tid] = b_dec[tid];
    for (int i = tid; i < 54 * 64; i += NTHR) {
        const int fr = i >> 6, l = i & 63;
        const int tau = fr / 9, kk = fr % 9;
        const int gam = tau >> 1, p = tau & 1;
        const int c = gam * 16 + 2 * j + p;
        const bf16* src = (kk < 8) ? &WhhP[(((size_t)c) * 8 + kk) * 512 + l * 8]
                                   : &WihP[((size_t)c) * 512 + l * 8];
        *(bf16x8*)&sWgt[((size_t)fr) * 512 + l * 8] = *(const bf16x8*)src;
    }

    // ---- GRU per-wave constants (wave = batch-tile m = w) ----
    const int m = w;
    float bcr[2][4], bcz[2][4], bcn[2][4], bnr[2][4];
    {
        const int c = cidx[grow0 + 16 * m + lm];
        #pragma unroll
        for (int p = 0; p < 2; ++p)
            #pragma unroll
            for (int r = 0; r < 4; ++r) {
                const int F = 32 * j + p * 16 + q4 + r;
                bcr[p][r] = bias_c[(size_t)c * 768 + F];
                bcz[p][r] = bias_c[(size_t)c * 768 + 256 + F];
                bcn[p][r] = bias_c[(size_t)c * 768 + 512 + F];
                bnr[p][r] = b_n[F];
            }
    }
    int dgru[2];
    #pragma unroll
    for (int p = 0; p < 2; ++p)
        dgru[p] = (j * 64 + ((4 * j + 2 * p + (q >> 1)) & 3) * 16 + lm) * 8 + (q & 1) * 4;

    // h0 = 0 (each block zeroes its 32-feat slice of every tile; wave w -> tile w)
    {
        bf16x4 z4;
        #pragma unroll
        for (int r = 0; r < 4; ++r) z4[r] = (bf16)0.f;
        st4g<FAST>(gY + m * 4096 + dgru[0], z4);
        st4g<FAST>(gY + m * 4096 + dgru[1], z4);
    }
    produce(fY, tid); ++eY;     // also covers the LDS weight staging (syncthreads inside)

    // ---- GRU scan (block-lockstep) ----
    f32x4 hreg[2] = {{0.f, 0.f, 0.f, 0.f}, {0.f, 0.f, 0.f, 0.f}};
    const f32x4 Z = {0.f, 0.f, 0.f, 0.f};
    for (int t = 0; t < T_SEQ; ++t) {
        bf16x8 ax;
        {
            const float* xp = x_seq + (((size_t)(grow0 + 16 * m + lm)) * T_SEQ + t) * 32 + q * 8;
            f32x4 xa = *(const f32x4*)xp;
            f32x4 xb = *(const f32x4*)(xp + 4);
            #pragma unroll
            for (int e = 0; e < 4; ++e) { ax[e] = (bf16)xa[e]; ax[4 + e] = (bf16)xb[e]; }
        }
        consume(fY, GSZ * eY, tid);      // all blocks wrote h(t) buffer
        const bf16* hs = ((t & 1) ? gYb : gY) + m * 4096 + lane * 8;
        bf16x8 a[8];
        ld4g<FAST>(hs, a[0], a[1], a[2], a[3]);
        ld4g<FAST>(hs + 2048, a[4], a[5], a[6], a[7]);
        vmwait();
        f32x4 rz[4] = {Z, Z, Z, Z}, nH[2] = {Z, Z}, nX[2] = {Z, Z};
        #pragma unroll
        for (int kk = 0; kk < 8; ++kk) {
            #pragma unroll
            for (int p = 0; p < 2; ++p) {
                rz[p]     = MFMA(*(const bf16x8*)&sWgt[((0 + p) * 9 + kk) * 512 + lane * 8], a[kk], rz[p]);
                rz[2 + p] = MFMA(*(const bf16x8*)&sWgt[((2 + p) * 9 + kk) * 512 + lane * 8], a[kk], rz[2 + p]);
                nH[p]     = MFMA(*(const bf16x8*)&sWgt[((4 + p) * 9 + kk) * 512 + lane * 8], a[kk], nH[p]);
            }
        }
        #pragma unroll
        for (int p = 0; p < 2; ++p) {
            rz[p]     = MFMA(*(const bf16x8*)&sWgt[((0 + p) * 9 + 8) * 512 + lane * 8], ax, rz[p]);
            rz[2 + p] = MFMA(*(const bf16x8*)&sWgt[((2 + p) * 9 + 8) * 512 + lane * 8], ax, rz[2 + p]);
            nX[p]     = MFMA(*(const bf16x8*)&sWgt[((4 + p) * 9 + 8) * 512 + lane * 8], ax, nX[p]);
        }
        bf16* hd = (((t + 1) & 1) ? gYb : gY) + m * 4096;
        #pragma unroll
        for (int p = 0; p < 2; ++p) {
            bf16x4 ov;
            #pragma unroll
            for (int r = 0; r < 4; ++r) {
                const float rg = sigm_f(rz[p][r] + bcr[p][r]);
                const float zg = sigm_f(rz[2 + p][r] + bcz[p][r]);
                const float nn = tanh_f(nX[p][r] + bcn[p][r] + rg * (nH[p][r] + bnr[p][r]));
                hreg[p][r] = nn + zg * (hreg[p][r] - nn);
                ov[r] = (bf16)hreg[p][r];
            }
            st4g<FAST>(hd + dgru[p], ov);
        }
        produce(fY, tid); ++eY;
    }
    // last produce's __syncthreads => all waves done reading GRU weights from LDS

    // ---- stage ODE weight slices; hand off h_final f32 via LDS ----
    bf16* sW0 = sWgt;            // 16384 elems
    bf16* sW1 = sWgt + 16384;    // 32768 elems
    bf16* sW2 = sWgt + 49152;    // 16384 elems
    for (int i = tid; i < 2048; i += NTHR)
        *(bf16x8*)&sW0[i * 8] = *(const bf16x8*)&W0p[(size_t)j * 16384 + i * 8];
    for (int i = tid; i < 4096; i += NTHR)
        *(bf16x8*)&sW1[i * 8] = *(const bf16x8*)&W1p[(size_t)j * 32768 + i * 8];
    for (int i = tid; i < 2048; i += NTHR)
        *(bf16x8*)&sW2[i * 8] = *(const bf16x8*)&W2p[(size_t)j * 16384 + i * 8];
    #pragma unroll
    for (int p = 0; p < 2; ++p)
        #pragma unroll
        for (int r = 0; r < 4; ++r)
            yx[((m * 32) + p * 16 + q4 + r) * 16 + lm] = hreg[p][r];
    __syncthreads();

    // ---- ODE wave roles (2-D tiling) ----
    const int nt01 = w >> 1, mh = w & 1, mb01 = mh * 4;   // L0/L1: feat tile, batch half
    const int nt2 = w >> 2, mq = w & 3, mb2 = mq * 2;     // L2: feat tile, batch quarter

    float b0w[4], b1w[4], b2w[4];
    #pragma unroll
    for (int r = 0; r < 4; ++r) {
        b0w[r] = b0[64 * j + nt01 * 16 + q4 + r];
        b1w[r] = b1[64 * j + nt01 * 16 + q4 + r];
        b2w[r] = b2[32 * j + nt2 * 16 + q4 + r];
    }
    f32x4 yreg[2], kreg[5][2];
    #pragma unroll
    for (int i = 0; i < 2; ++i)
        #pragma unroll
        for (int r = 0; r < 4; ++r)
            yreg[i][r] = yx[((mb2 + i) * 32 + nt2 * 16 + q4 + r) * 16 + lm];

    const bf16* sW0l = sW0 + nt01 * 8 * 512 + lane * 8;
    const bf16* sW1l = sW1 + nt01 * 16 * 512 + lane * 8;
    const bf16* sW2l = sW2 + nt2 * 16 * 512 + lane * 8;
    const bf16* gYl  = gY + mb01 * 4096 + lane * 8;
    const bf16* gH1l = gH1 + mb01 * 8192 + lane * 8;
    const bf16* gH2l = gH2 + mb2 * 8192 + lane * 8;
    const int d01 = ((2 * j + (nt01 >> 1)) * 64 + ((8 * j + 2 * nt01 + (q >> 1)) & 3) * 16 + lm) * 8 + (q & 1) * 4;
    const int d2  = (j * 64 + ((4 * j + 2 * nt2 + (q >> 1)) & 3) * 16 + lm) * 8 + (q & 1) * 4;
    bf16* gH1d = gH1 + mb01 * 8192 + d01;
    bf16* gH2d = gH2 + mb01 * 8192 + d01;
    bf16* gYd  = gY + mb2 * 4096 + d2;

    // ---- Tsit5 loop (consume-before-stage, round-5 pattern) ----
    const int NSS = H * 10;
    for (int ss = 0; ss < NSS; ++ss) {
        consume(fY, GSZ * eY, tid);
        if (ss && ss % 10 == 0)
            dec_unit<FAST>(gY, sWdec, sBdec, out, g, j, w, lane, H, ss / 10 - 1);
        ode_stage<0, FAST>(sW0l, sW1l, sW2l, gYl, gH1d, gH1l, gH2d, gH2l, gYd,
                           fY, fH1, fH2, tid, b0w, b1w, b2w, yreg, kreg, eY, eH1, eH2);
        consume(fY, GSZ * eY, tid);
        ode_stage<1, FAST>(sW0l, sW1l, sW2l, gYl, gH1d, gH1l, gH2d, gH2l, gYd,
                           fY, fH1, fH2, tid, b0w, b1w, b2w, yreg, kreg, eY, eH1, eH2);
        consume(fY, GSZ * eY, tid);
        ode_stage<2, FAST>(sW0l, sW1l, sW2l, gYl, gH1d, gH1l, gH2d, gH2l, gYd,
                           fY, fH1, fH2, tid, b0w, b1w, b2w, yreg, kreg, eY, eH1, eH2);
        consume(fY, GSZ * eY, tid);
        ode_stage<3, FAST>(sW0l, sW1l, sW2l, gYl, gH1d, gH1l, gH2d, gH2l, gYd,
                           fY, fH1, fH2, tid, b0w, b1w, b2w, yreg, kreg, eY, eH1, eH2);
        consume(fY, GSZ * eY, tid);
        ode_stage<4, FAST>(sW0l, sW1l, sW2l, gYl, gH1d, gH1l, gH2d, gH2l, gYd,
                           fY, fH1, fH2, tid, b0w, b1w, b2w, yreg, kreg, eY, eH1, eH2);
        consume(fY, GSZ * eY, tid);
        ode_stage<5, FAST>(sW0l, sW1l, sW2l, gYl, gH1d, gH1l, gH2d, gH2l, gYd,
                           fY, fH1, fH2, tid, b0w, b1w, b2w, yreg, kreg, eY, eH1, eH2);
    }
    consume(fY, GSZ * eY, tid);
    dec_unit<FAST>(gY, sWdec, sBdec, out, g, j, w, lane, H, H - 1);
}

__global__ void __launch_bounds__(NTHR, 2)
k_main(const float* __restrict__ x_seq, const int* __restrict__ cidx,
       const float* __restrict__ b_n, const float* __restrict__ b0,
       const float* __restrict__ b1, const float* __restrict__ b2,
       const float* __restrict__ W_dec, const float* __restrict__ b_dec,
       char* __restrict__ ws, float* __restrict__ out, int H) {
    __shared__ __align__(16) char SM[155712];
    const int tid = threadIdx.x, b = blockIdx.x;
    const int x8 = b & 7, rr = b >> 3, mg = rr >> 3, j = rr & 7;
    const int g = x8 * 4 + mg;

    u32* xmap = (u32*)(ws + WS_MAP);
    u32* gctr = (u32*)(ws + WS_MAP + 1024);
    u32 xcc;
    asm volatile("s_getreg_b32 %0, hwreg(HW_REG_XCC_ID)" : "=s"(xcc));
    if (tid == 0) {
        __hip_atomic_store(&xmap[b], xcc, __ATOMIC_RELAXED, __HIP_MEMORY_SCOPE_AGENT);
        __hip_atomic_fetch_add(gctr, 1u, __ATOMIC_RELAXED, __HIP_MEMORY_SCOPE_AGENT);
        while (__hip_atomic_load(gctr, __ATOMIC_RELAXED, __HIP_MEMORY_SCOPE_AGENT) < NBLK)
            __builtin_amdgcn_s_sleep(8);
    }
    __syncthreads();
    u32* mapL = (u32*)(SM + 139264);
    if (tid < NBLK)
        mapL[tid] = __hip_atomic_load(&xmap[tid], __ATOMIC_RELAXED, __HIP_MEMORY_SCOPE_AGENT);
    __syncthreads();
    int* fastP = (int*)(SM + 155680);
    if (tid == 0) {
        const u32 my = mapL[b];
        int cnt = 0;
        for (int i = 0; i < NBLK; ++i) cnt += (mapL[i] == my) ? 1 : 0;
        int ok = (cnt == 32) ? 1 : 0;
        for (int i = 0; i < GSZ; ++i) ok &= (mapL[x8 + 8 * (mg * 8 + i)] == my) ? 1 : 0;
        *fastP = ok;
    }
    __syncthreads();
    const int fastf = *fastP;
    __syncthreads();

    if (fastf)
        body<true>(x_seq, cidx, b_n, b0, b1, b2, W_dec, b_dec, ws, out, (char*)SM, H, g, j);
    else
        body<false>(x_seq, cidx, b_n, b0, b1, b2, W_dec, b_dec, ws, out, (char*)SM, H, g, j);
}

// Pack fp32 weight [OUT][Ksrc] (cols koff..koff+K) into MFMA A-fragment order bf16:
// frag f = c*(K/32)+kk; lane's 8 elems = row c*16+(lane&15), k = kk*32+(lane>>4)*8+j
__global__ void k_pack(const float* __restrict__ src, bf16* __restrict__ dst,
                       int OUT, int K, int Ksrc, int koff) {
    const int total = (OUT * K) >> 3;
    for (int gg = blockIdx.x * blockDim.x + threadIdx.x; gg < total; gg += gridDim.x * blockDim.x) {
        const int lane = gg & 63, f = gg >> 6;
        const int KK = K >> 5;
        const int kk = f % KK, c = f / KK;
        const int col = c * 16 + (lane & 15);
        const int k0 = kk * 32 + ((lane >> 4) << 3);
        bf16x8 o;
        #pragma unroll
        for (int jj = 0; jj < 8; ++jj) o[jj] = (bf16)src[(size_t)col * Ksrc + koff + k0 + jj];
        *(bf16x8*)&dst[(size_t)gg * 8] = o;
    }
}

__global__ void k_bias(const float* __restrict__ W_ih, const float* __restrict__ b_ih,
                       float* __restrict__ bias_c) {
    const int i = blockIdx.x * blockDim.x + threadIdx.x;
    if (i < 64 * 768) {
        const int c = i / 768, n = i - c * 768;
        bias_c[i] = W_ih[(size_t)n * 96 + 32 + c] + b_ih[n];
    }
}

extern "C" void kernel_launch(void* const* d_in, const int* in_sizes, int n_in,
                              void* d_out, int out_size, void* d_ws, size_t ws_size,
                              hipStream_t stream) {
    const float* x_seq = (const float*)d_in[0];
    const int*   cidx  = (const int*)d_in[1];
    const float* W_ih  = (const float*)d_in[3];
    const float* W_hh  = (const float*)d_in[4];
    const float* b_ih  = (const float*)d_in[5];
    const float* b_n   = (const float*)d_in[6];
    const float* W0    = (const float*)d_in[7];
    const float* b0    = (const float*)d_in[8];
    const float* W1    = (const float*)d_in[9];
    const float* b1    = (const float*)d_in[10];
    const float* W2    = (const float*)d_in[11];
    const float* b2    = (const float*)d_in[12];
    const float* W_dec = (const float*)d_in[13];
    const float* b_dec = (const float*)d_in[14];
    float* out = (float*)d_out;
    const int H = out_size / (B_TOT * NT_OUT);
    char* ws = (char*)d_ws;

    // zero flags + xcd map + grid counter (every launch -> graph-replay safe)
    hipMemsetAsync(ws + WS_FLG, 0, 8192, stream);

    k_pack<<<64, 256, 0, stream>>>(W0, (bf16*)(ws + WS_W0), 512, 256, 256, 0);
    k_pack<<<128, 256, 0, stream>>>(W1, (bf16*)(ws + WS_W1), 512, 512, 512, 0);
    k_pack<<<64, 256, 0, stream>>>(W2, (bf16*)(ws + WS_W2), 256, 512, 512, 0);
    k_pack<<<96, 256, 0, stream>>>(W_hh, (bf16*)(ws + WS_WHH), 768, 256, 256, 0);
    k_pack<<<12, 256, 0, stream>>>(W_ih, (bf16*)(ws + WS_WIH), 768, 32, 96, 0);
    k_bias<<<(64 * 768 + 255) / 256, 256, 0, stream>>>(W_ih, b_ih, (float*)(ws + WS_BC));

    k_main<<<NBLK, NTHR, 0, stream>>>(x_seq, cidx, b_n, b0, b1, b2, W_dec, b_dec,
                                      ws, out, H);
}

// Round 9
// 6384.303 us; speedup vs baseline: 1.8850x; 1.8850x over previous
//
#include <hip/hip_runtime.h>

typedef __bf16 bf16;
typedef __bf16 bf16x8 __attribute__((ext_vector_type(8)));
typedef __bf16 bf16x4 __attribute__((ext_vector_type(4)));
typedef float  f32x4  __attribute__((ext_vector_type(4)));
typedef unsigned int u32;

#define B_TOT 4096
#define T_SEQ 64
#define NT_OUT 8
#define NTHR 512
#define NBLK 256
#define GSZ  8

// ---- ws layout (bytes) ----
#define WS_W0   0           // 512x256 bf16 packed frags
#define WS_W1   262144
#define WS_W2   786432
#define WS_WHH  1048576
#define WS_WIH  1441792
#define WS_BC   1490944     // 64x768 f32
#define WS_GY   1703936     // 32 groups x 64KB   (y_stage / GRU h buf0)
#define WS_GYB  3801088     // 32 x 64KB          (GRU h buf1)
#define WS_GH1  5898240     // 32 x 128KB
#define WS_GH2  10092544    // 32 x 128KB
#define WS_FLG  14286848    // 32 groups x 128B  (fY@0, fH1@+64B, fH2@+128B)
#define WS_MAP  14290944    // 256 u32 xcd map; gctr @ +1024

// Tsit5 tableau
constexpr float A21 = 0.161f;
constexpr float A31 = -0.008480655492356989f, A32 = 0.335480655492357f;
constexpr float A41 = 2.8971530571054935f, A42 = -6.359448489975075f, A43 = 4.362295432869581f;
constexpr float A51 = 5.325864828439257f, A52 = -11.748883564062828f, A53 = 7.4955393428898365f, A54 = -0.09249506636175525f;
constexpr float A61 = 5.86145544294642f, A62 = -12.92096931784711f, A63 = 8.159367898576159f, A64 = -0.071584973281401f, A65 = -0.028269050394068383f;
constexpr float BC1 = 0.09646076681806523f, BC2 = 0.01f, BC3 = 0.4798896504144996f;
constexpr float BC4 = 1.379008574103742f, BC5 = -3.290069515436081f, BC6 = 2.324710524099774f;
constexpr float DT = 0.1f;
constexpr float BROW[5][5] = {
    {A21, 0, 0, 0, 0},
    {A31, A32, 0, 0, 0},
    {A41, A42, A43, 0, 0},
    {A51, A52, A53, A54, 0},
    {A61, A62, A63, A64, A65}};
constexpr float FCF[6] = {BC1, BC2, BC3, BC4, BC5, BC6};

__device__ __forceinline__ f32x4 MFMA(bf16x8 a, bf16x8 b, f32x4 c) {
    return __builtin_amdgcn_mfma_f32_16x16x32_bf16(a, b, c, 0, 0, 0);
}
__device__ __forceinline__ float eluf(float x) { return x > 0.f ? x : __expf(x) - 1.f; }
__device__ __forceinline__ float sigm_f(float x) { return 1.f / (1.f + __expf(-x)); }
__device__ __forceinline__ float tanh_f(float x) { return 1.f - 2.f / (__expf(2.f * x) + 1.f); }

// ---- coherent global access (FAST: group formed on one XCD -> sc0 only) ----
template<bool FAST>
__device__ __forceinline__ void ld4g(const bf16* p, bf16x8& a0, bf16x8& a1, bf16x8& a2, bf16x8& a3) {
    if constexpr (FAST) {
        asm volatile(
            "global_load_dwordx4 %0, %4, off sc0\n\t"
            "global_load_dwordx4 %1, %4, off offset:1024 sc0\n\t"
            "global_load_dwordx4 %2, %4, off offset:2048 sc0\n\t"
            "global_load_dwordx4 %3, %4, off offset:3072 sc0"
            : "=&v"(a0), "=&v"(a1), "=&v"(a2), "=&v"(a3) : "v"(p) : "memory");
    } else {
        asm volatile(
            "global_load_dwordx4 %0, %4, off sc0 sc1\n\t"
            "global_load_dwordx4 %1, %4, off offset:1024 sc0 sc1\n\t"
            "global_load_dwordx4 %2, %4, off offset:2048 sc0 sc1\n\t"
            "global_load_dwordx4 %3, %4, off offset:3072 sc0 sc1"
            : "=&v"(a0), "=&v"(a1), "=&v"(a2), "=&v"(a3) : "v"(p) : "memory");
    }
}
template<bool FAST>
__device__ __forceinline__ bf16x8 ld1g(const bf16* p) {
    bf16x8 a;
    if constexpr (FAST)
        asm volatile("global_load_dwordx4 %0, %1, off sc0\n\ts_waitcnt vmcnt(0)"
                     : "=v"(a) : "v"(p) : "memory");
    else
        asm volatile("global_load_dwordx4 %0, %1, off sc0 sc1\n\ts_waitcnt vmcnt(0)"
                     : "=v"(a) : "v"(p) : "memory");
    return a;
}
template<bool FAST>
__device__ __forceinline__ void st4g(bf16* p, bf16x4 v) {
    if constexpr (FAST) *(bf16x4*)p = v;
    else asm volatile("global_store_dwordx2 %0, %1, off sc0 sc1" :: "v"(p), "v"(v) : "memory");
}
__device__ __forceinline__ void vmwait() {
    asm volatile("s_waitcnt vmcnt(0)" ::: "memory");
    __builtin_amdgcn_sched_barrier(0);
}

// ---- block-lockstep group rendezvous (round-5 proven semantics) ----
__device__ __forceinline__ void produce(u32* f, int tid) {
    asm volatile("s_waitcnt vmcnt(0)" ::: "memory");   // own wave's stores acked
    __syncthreads();                                   // all waves drained
    if (tid == 0) __hip_atomic_fetch_add(f, 1u, __ATOMIC_RELAXED, __HIP_MEMORY_SCOPE_AGENT);
}
__device__ __forceinline__ void consume(const u32* f, u32 tgt, int tid) {
    if (tid == 0) {
        while (__hip_atomic_load(f, __ATOMIC_RELAXED, __HIP_MEMORY_SCOPE_AGENT) < tgt)
            __builtin_amdgcn_s_sleep(1);
    }
    __syncthreads();
}

// ---- one Tsit5 stage; wave = batch tile m = w (no redundant act reads) ----
template<int ST, bool FAST>
__device__ __forceinline__ void ode_stage(
    const bf16* sW0, const bf16* sW1, const bf16* sW2,
    bf16* gY, bf16* gH1, bf16* gH2,
    u32* fY, u32* fH1, u32* fH2, int tid, int w, int lane,
    const f32x4 (&b0v)[4], const f32x4 (&b1v)[4], const f32x4 (&b2v)[2],
    const int (&dA)[4], const int (&dY)[2],
    f32x4 (&yreg)[2], f32x4 (&kreg)[5][2],
    u32& eY, u32& eH1, u32& eH2) {
    const f32x4 Z = {0.f, 0.f, 0.f, 0.f};
    // ---- L0: h1-slice = elu(W0s x y^T + b0s), A=weight(LDS), B=act(L2) ----
    {
        bf16x8 a[8];
        const bf16* p = gY + w * 4096 + lane * 8;
        ld4g<FAST>(p, a[0], a[1], a[2], a[3]);
        ld4g<FAST>(p + 2048, a[4], a[5], a[6], a[7]);
        vmwait();
        f32x4 acc[4] = {Z, Z, Z, Z};
        #pragma unroll
        for (int kk = 0; kk < 8; ++kk)
            #pragma unroll
            for (int nt = 0; nt < 4; ++nt)
                acc[nt] = MFMA(*(const bf16x8*)&sW0[(nt * 8 + kk) * 512 + lane * 8], a[kk], acc[nt]);
        #pragma unroll
        for (int nt = 0; nt < 4; ++nt) {
            bf16x4 ov;
            #pragma unroll
            for (int r = 0; r < 4; ++r) ov[r] = (bf16)eluf(acc[nt][r] + b0v[nt][r]);
            st4g<FAST>(gH1 + w * 8192 + dA[nt], ov);
        }
    }
    produce(fH1, tid); ++eH1;
    consume(fH1, GSZ * eH1, tid);
    // ---- L1: h2-slice = elu(W1s x h1^T + b1s) ----
    {
        bf16x8 a[16];
        const bf16* p = gH1 + w * 8192 + lane * 8;
        ld4g<FAST>(p, a[0], a[1], a[2], a[3]);
        ld4g<FAST>(p + 2048, a[4], a[5], a[6], a[7]);
        ld4g<FAST>(p + 4096, a[8], a[9], a[10], a[11]);
        ld4g<FAST>(p + 6144, a[12], a[13], a[14], a[15]);
        vmwait();
        f32x4 acc[4] = {Z, Z, Z, Z};
        #pragma unroll
        for (int kk = 0; kk < 16; ++kk)
            #pragma unroll
            for (int nt = 0; nt < 4; ++nt)
                acc[nt] = MFMA(*(const bf16x8*)&sW1[(nt * 16 + kk) * 512 + lane * 8], a[kk], acc[nt]);
        #pragma unroll
        for (int nt = 0; nt < 4; ++nt) {
            bf16x4 ov;
            #pragma unroll
            for (int r = 0; r < 4; ++r) ov[r] = (bf16)eluf(acc[nt][r] + b1v[nt][r]);
            st4g<FAST>(gH2 + w * 8192 + dA[nt], ov);
        }
    }
    produce(fH2, tid); ++eH2;
    consume(fH2, GSZ * eH2, tid);
    // ---- L2: k-slice = W2s x h2^T + b2s; Tsit5 build in registers ----
    {
        bf16x8 a[16];
        const bf16* p = gH2 + w * 8192 + lane * 8;
        ld4g<FAST>(p, a[0], a[1], a[2], a[3]);
        ld4g<FAST>(p + 2048, a[4], a[5], a[6], a[7]);
        ld4g<FAST>(p + 4096, a[8], a[9], a[10], a[11]);
        ld4g<FAST>(p + 6144, a[12], a[13], a[14], a[15]);
        vmwait();
        f32x4 acc[2] = {Z, Z};
        #pragma unroll
        for (int kk = 0; kk < 16; ++kk)
            #pragma unroll
            for (int nt = 0; nt < 2; ++nt)
                acc[nt] = MFMA(*(const bf16x8*)&sW2[(nt * 16 + kk) * 512 + lane * 8], a[kk], acc[nt]);
        #pragma unroll
        for (int nt = 0; nt < 2; ++nt) {
            f32x4 kv;
            #pragma unroll
            for (int r = 0; r < 4; ++r) kv[r] = acc[nt][r] + b2v[nt][r];
            f32x4 yst;
            if constexpr (ST < 5) {
                kreg[ST][nt] = kv;
                yst = yreg[nt];
                #pragma unroll
                for (int s = 0; s <= ST; ++s) {
                    const float c = DT * BROW[ST][s];
                    #pragma unroll
                    for (int r = 0; r < 4; ++r) yst[r] += c * kreg[s][nt][r];
                }
            } else {
                #pragma unroll
                for (int s = 0; s < 5; ++s) {
                    const float c = DT * FCF[s];
                    #pragma unroll
                    for (int r = 0; r < 4; ++r) yreg[nt][r] += c * kreg[s][nt][r];
                }
                #pragma unroll
                for (int r = 0; r < 4; ++r) yreg[nt][r] += (DT * FCF[5]) * kv[r];
                yst = yreg[nt];
            }
            bf16x4 ov;
            #pragma unroll
            for (int r = 0; r < 4; ++r) ov[r] = (bf16)yst[r];
            st4g<FAST>(gY + w * 4096 + dY[nt], ov);
        }
    }
    produce(fY, tid); ++eY;
}

// ---- decode: block rank j emits its group's batch tile j for unit u ----
template<bool FAST>
__device__ __forceinline__ void dec_unit(const bf16* gY, const float* sWdec, const float* sBdec,
                                         float* out, int g, int j, int w, int lane, int H, int u) {
    const int rloc = 2 * w + (lane >> 5);
    const int li = lane & 31;
    const bf16* p = gY + (size_t)j * 4096 + (((li >> 2) * 64 + (li & 3) * 16 + rloc)) * 8;
    bf16x8 yv = ld1g<FAST>(p);
    const int f0 = li * 8;
    float acc[8];
    #pragma unroll
    for (int t = 0; t < 8; ++t) acc[t] = 0.f;
    #pragma unroll
    for (int e = 0; e < 8; ++e) {
        const float yf = (float)yv[e];
        #pragma unroll
        for (int t = 0; t < 8; ++t) acc[t] += yf * sWdec[t * 256 + f0 + e];
    }
    #pragma unroll
    for (int k = 1; k < 32; k <<= 1)
        #pragma unroll
        for (int t = 0; t < 8; ++t) acc[t] += __shfl_xor(acc[t], k, 64);
    if (li == 0) {
        const size_t row = (size_t)g * 128 + 16 * j + rloc;
        #pragma unroll
        for (int t = 0; t < 8; ++t) out[(row * H + u) * NT_OUT + t] = acc[t] + sBdec[t];
    }
}

template<bool FAST>
__device__ void body(const float* __restrict__ x_seq, const int* __restrict__ cidx,
                     const float* __restrict__ b_n, const float* __restrict__ b0,
                     const float* __restrict__ b1, const float* __restrict__ b2,
                     const float* __restrict__ W_dec, const float* __restrict__ b_dec,
                     char* __restrict__ ws, float* __restrict__ out,
                     bf16* sWgt, float* sWdec, float* sBdec,
                     int H, int g, int j) {
    const int tid = threadIdx.x, w = tid >> 6, lane = tid & 63;
    const int lm = lane & 15, q = lane >> 4, q4 = q << 2;
    const int grow0 = g * 128;

    const bf16* W0p  = (const bf16*)(ws + WS_W0);
    const bf16* W1p  = (const bf16*)(ws + WS_W1);
    const bf16* W2p  = (const bf16*)(ws + WS_W2);
    const bf16* WhhP = (const bf16*)(ws + WS_WHH);
    const bf16* WihP = (const bf16*)(ws + WS_WIH);
    const float* bias_c = (const float*)(ws + WS_BC);
    bf16* gY  = (bf16*)(ws + WS_GY)  + (size_t)g * 32768;
    bf16* gYb = (bf16*)(ws + WS_GYB) + (size_t)g * 32768;
    bf16* gH1 = (bf16*)(ws + WS_GH1) + (size_t)g * 65536;
    bf16* gH2 = (bf16*)(ws + WS_GH2) + (size_t)g * 65536;
    u32* fl  = (u32*)(ws + WS_FLG + (size_t)g * 128);
    u32 *fY = fl, *fH1 = fl + 16, *fH2 = fl + 32;

    u32 eY = 0, eH1 = 0, eH2 = 0;

    // ---- stage decode weights + GRU weight slices into LDS ----
    for (int i = tid; i < 2048; i += NTHR) sWdec[i] = W_dec[i];
    if (tid < 8) sBdec[tid] = b_dec[tid];
    for (int i = tid; i < 54 * 64; i += NTHR) {
        const int fr = i >> 6, l = i & 63;
        const int tau = fr / 9, kk = fr % 9;
        const int gam = tau >> 1, p = tau & 1;
        const int c = gam * 16 + 2 * j + p;
        const bf16* src = (kk < 8) ? &WhhP[(((size_t)c) * 8 + kk) * 512 + l * 8]
                                   : &WihP[((size_t)c) * 512 + l * 8];
        *(bf16x8*)&sWgt[((size_t)fr) * 512 + l * 8] = *(const bf16x8*)src;
    }

    // ---- GRU per-wave constants (wave = batch tile m = w) ----
    const int m = w;
    float bcr[2][4], bcz[2][4], bcn[2][4], bnr[2][4];
    {
        const int c = cidx[grow0 + 16 * m + lm];
        #pragma unroll
        for (int p = 0; p < 2; ++p)
            #pragma unroll
            for (int r = 0; r < 4; ++r) {
                const int F = 32 * j + p * 16 + q4 + r;
                bcr[p][r] = bias_c[(size_t)c * 768 + F];
                bcz[p][r] = bias_c[(size_t)c * 768 + 256 + F];
                bcn[p][r] = bias_c[(size_t)c * 768 + 512 + F];
                bnr[p][r] = b_n[F];
            }
    }
    int dY[2];
    #pragma unroll
    for (int p = 0; p < 2; ++p)
        dY[p] = (j * 64 + ((4 * j + 2 * p + (q >> 1)) & 3) * 16 + lm) * 8 + (q & 1) * 4;

    // h0 = 0 (wave w zeroes its feat slice of its tile)
    {
        bf16x4 z4;
        #pragma unroll
        for (int r = 0; r < 4; ++r) z4[r] = (bf16)0.f;
        st4g<FAST>(gY + m * 4096 + dY[0], z4);
        st4g<FAST>(gY + m * 4096 + dY[1], z4);
    }
    produce(fY, tid); ++eY;     // also covers LDS weight staging (syncthreads inside)

    // ---- GRU scan (block-lockstep) ----
    f32x4 hreg[2] = {{0.f, 0.f, 0.f, 0.f}, {0.f, 0.f, 0.f, 0.f}};
    const f32x4 Z = {0.f, 0.f, 0.f, 0.f};
    for (int t = 0; t < T_SEQ; ++t) {
        bf16x8 ax;
        {
            const float* xp = x_seq + (((size_t)(grow0 + 16 * m + lm)) * T_SEQ + t) * 32 + q * 8;
            f32x4 xa = *(const f32x4*)xp;
            f32x4 xb = *(const f32x4*)(xp + 4);
            #pragma unroll
            for (int e = 0; e < 4; ++e) { ax[e] = (bf16)xa[e]; ax[4 + e] = (bf16)xb[e]; }
        }
        consume(fY, GSZ * eY, tid);      // all blocks wrote h(t) buffer
        const bf16* hs = ((t & 1) ? gYb : gY) + m * 4096 + lane * 8;
        bf16x8 a[8];
        ld4g<FAST>(hs, a[0], a[1], a[2], a[3]);
        ld4g<FAST>(hs + 2048, a[4], a[5], a[6], a[7]);
        vmwait();
        f32x4 rz[4] = {Z, Z, Z, Z}, nH[2] = {Z, Z}, nX[2] = {Z, Z};
        #pragma unroll
        for (int kk = 0; kk < 8; ++kk) {
            #pragma unroll
            for (int p = 0; p < 2; ++p) {
                rz[p]     = MFMA(*(const bf16x8*)&sWgt[((0 + p) * 9 + kk) * 512 + lane * 8], a[kk], rz[p]);
                rz[2 + p] = MFMA(*(const bf16x8*)&sWgt[((2 + p) * 9 + kk) * 512 + lane * 8], a[kk], rz[2 + p]);
                nH[p]     = MFMA(*(const bf16x8*)&sWgt[((4 + p) * 9 + kk) * 512 + lane * 8], a[kk], nH[p]);
            }
        }
        #pragma unroll
        for (int p = 0; p < 2; ++p) {
            rz[p]     = MFMA(*(const bf16x8*)&sWgt[((0 + p) * 9 + 8) * 512 + lane * 8], ax, rz[p]);
            rz[2 + p] = MFMA(*(const bf16x8*)&sWgt[((2 + p) * 9 + 8) * 512 + lane * 8], ax, rz[2 + p]);
            nX[p]     = MFMA(*(const bf16x8*)&sWgt[((4 + p) * 9 + 8) * 512 + lane * 8], ax, nX[p]);
        }
        bf16* hd = (((t + 1) & 1) ? gYb : gY) + m * 4096;
        #pragma unroll
        for (int p = 0; p < 2; ++p) {
            bf16x4 ov;
            #pragma unroll
            for (int r = 0; r < 4; ++r) {
                const float rg = sigm_f(rz[p][r] + bcr[p][r]);
                const float zg = sigm_f(rz[2 + p][r] + bcz[p][r]);
                const float nn = tanh_f(nX[p][r] + bcn[p][r] + rg * (nH[p][r] + bnr[p][r]));
                hreg[p][r] = nn + zg * (hreg[p][r] - nn);
                ov[r] = (bf16)hreg[p][r];
            }
            st4g<FAST>(hd + dY[p], ov);
        }
        produce(fY, tid); ++eY;
    }
    // last produce's __syncthreads => all waves done with GRU weights in LDS

    // ---- stage ODE weight slices (overwrite GRU region) ----
    bf16* sW0 = sWgt;            // 16384 elems
    bf16* sW1 = sWgt + 16384;    // 32768 elems
    bf16* sW2 = sWgt + 49152;    // 16384 elems
    for (int i = tid; i < 2048; i += NTHR)
        *(bf16x8*)&sW0[i * 8] = *(const bf16x8*)&W0p[(size_t)j * 16384 + i * 8];
    for (int i = tid; i < 4096; i += NTHR)
        *(bf16x8*)&sW1[i * 8] = *(const bf16x8*)&W1p[(size_t)j * 32768 + i * 8];
    for (int i = tid; i < 2048; i += NTHR)
        *(bf16x8*)&sW2[i * 8] = *(const bf16x8*)&W2p[(size_t)j * 16384 + i * 8];
    __syncthreads();

    // ---- per-wave ODE constants; yreg = hreg directly (identical ownership) ----
    f32x4 b0v[4], b1v[4], b2v[2];
    #pragma unroll
    for (int nt = 0; nt < 4; ++nt) {
        b0v[nt] = *(const f32x4*)&b0[64 * j + nt * 16 + q4];
        b1v[nt] = *(const f32x4*)&b1[64 * j + nt * 16 + q4];
    }
    #pragma unroll
    for (int nt = 0; nt < 2; ++nt) b2v[nt] = *(const f32x4*)&b2[32 * j + nt * 16 + q4];
    int dA[4];
    #pragma unroll
    for (int nt = 0; nt < 4; ++nt)
        dA[nt] = ((2 * j + (nt >> 1)) * 64 + ((8 * j + 2 * nt + (q >> 1)) & 3) * 16 + lm) * 8 + (q & 1) * 4;

    f32x4 yreg[2] = {hreg[0], hreg[1]};
    f32x4 kreg[5][2];

    // ---- Tsit5 loop (consume-before-stage) ----
    const int NSS = H * 10;
    for (int ss = 0; ss < NSS; ++ss) {
        consume(fY, GSZ * eY, tid);
        if (ss && ss % 10 == 0)
            dec_unit<FAST>(gY, sWdec, sBdec, out, g, j, w, lane, H, ss / 10 - 1);
        ode_stage<0, FAST>(sW0, sW1, sW2, gY, gH1, gH2, fY, fH1, fH2, tid, w, lane,
                           b0v, b1v, b2v, dA, dY, yreg, kreg, eY, eH1, eH2);
        consume(fY, GSZ * eY, tid);
        ode_stage<1, FAST>(sW0, sW1, sW2, gY, gH1, gH2, fY, fH1, fH2, tid, w, lane,
                           b0v, b1v, b2v, dA, dY, yreg, kreg, eY, eH1, eH2);
        consume(fY, GSZ * eY, tid);
        ode_stage<2, FAST>(sW0, sW1, sW2, gY, gH1, gH2, fY, fH1, fH2, tid, w, lane,
                           b0v, b1v, b2v, dA, dY, yreg, kreg, eY, eH1, eH2);
        consume(fY, GSZ * eY, tid);
        ode_stage<3, FAST>(sW0, sW1, sW2, gY, gH1, gH2, fY, fH1, fH2, tid, w, lane,
                           b0v, b1v, b2v, dA, dY, yreg, kreg, eY, eH1, eH2);
        consume(fY, GSZ * eY, tid);
        ode_stage<4, FAST>(sW0, sW1, sW2, gY, gH1, gH2, fY, fH1, fH2, tid, w, lane,
                           b0v, b1v, b2v, dA, dY, yreg, kreg, eY, eH1, eH2);
        consume(fY, GSZ * eY, tid);
        ode_stage<5, FAST>(sW0, sW1, sW2, gY, gH1, gH2, fY, fH1, fH2, tid, w, lane,
                           b0v, b1v, b2v, dA, dY, yreg, kreg, eY, eH1, eH2);
    }
    consume(fY, GSZ * eY, tid);
    dec_unit<FAST>(gY, sWdec, sBdec, out, g, j, w, lane, H, H - 1);
}

__global__ void __launch_bounds__(NTHR, 2)
k_main(const float* __restrict__ x_seq, const int* __restrict__ cidx,
       const float* __restrict__ b_n, const float* __restrict__ b0,
       const float* __restrict__ b1, const float* __restrict__ b2,
       const float* __restrict__ W_dec, const float* __restrict__ b_dec,
       char* __restrict__ ws, float* __restrict__ out, int H) {
    __shared__ __align__(16) bf16 sWgt[65536];     // 128 KB
    __shared__ __align__(16) float sWdec[2048];    // 8 KB
    __shared__ float sBdec[8];
    __shared__ u32 mapL[NBLK];
    __shared__ int sMeta[3];

    const int tid = threadIdx.x, b = blockIdx.x;

    // ---- XCD map exchange (device-scope) ----
    u32* xmap = (u32*)(ws + WS_MAP);
    u32* gctr = (u32*)(ws + WS_MAP + 1024);
    u32 xcc;
    asm volatile("s_getreg_b32 %0, hwreg(HW_REG_XCC_ID)" : "=s"(xcc));
    if (tid == 0) {
        __hip_atomic_store(&xmap[b], xcc, __ATOMIC_RELEASE, __HIP_MEMORY_SCOPE_AGENT);
        __hip_atomic_fetch_add(gctr, 1u, __ATOMIC_ACQ_REL, __HIP_MEMORY_SCOPE_AGENT);
        while (__hip_atomic_load(gctr, __ATOMIC_ACQUIRE, __HIP_MEMORY_SCOPE_AGENT) < NBLK)
            __builtin_amdgcn_s_sleep(8);
    }
    __syncthreads();
    if (tid < NBLK)
        mapL[tid] = __hip_atomic_load(&xmap[tid], __ATOMIC_ACQUIRE, __HIP_MEMORY_SCOPE_AGENT);
    __syncthreads();

    // ---- dynamic group formation: groups = 8 blocks co-resident on one XCD ----
    if (tid == 0) {
        int cnt[8] = {0, 0, 0, 0, 0, 0, 0, 0};
        int rank = 0, bad = 0;
        const u32 my = mapL[b];
        for (int i = 0; i < NBLK; ++i) {
            const u32 x = mapL[i];
            if (x > 7u) bad = 1;
            else cnt[x]++;
            if (i < b && x == my) ++rank;
        }
        int ok = !bad;
        #pragma unroll
        for (int i = 0; i < 8; ++i) ok &= (cnt[i] == 32);
        sMeta[0] = ok;
        sMeta[1] = ok ? (int)(my * 4 + (rank >> 3)) : ((b & 7) * 4 + (b >> 6));
        sMeta[2] = ok ? (rank & 7) : ((b >> 3) & 7);
    }
    __syncthreads();
    const int ok = sMeta[0], g = sMeta[1], j = sMeta[2];
    __syncthreads();

    if (ok)
        body<true>(x_seq, cidx, b_n, b0, b1, b2, W_dec, b_dec, ws, out,
                   sWgt, sWdec, sBdec, H, g, j);
    else
        body<false>(x_seq, cidx, b_n, b0, b1, b2, W_dec, b_dec, ws, out,
                    sWgt, sWdec, sBdec, H, g, j);
}

// Pack fp32 weight [OUT][Ksrc] (cols koff..koff+K) into MFMA A-fragment order bf16:
// frag f = c*(K/32)+kk; lane's 8 elems = row c*16+(lane&15), k = kk*32+(lane>>4)*8+j
__global__ void k_pack(const float* __restrict__ src, bf16* __restrict__ dst,
                       int OUT, int K, int Ksrc, int koff) {
    const int total = (OUT * K) >> 3;
    for (int gg = blockIdx.x * blockDim.x + threadIdx.x; gg < total; gg += gridDim.x * blockDim.x) {
        const int lane = gg & 63, f = gg >> 6;
        const int KK = K >> 5;
        const int kk = f % KK, c = f / KK;
        const int col = c * 16 + (lane & 15);
        const int k0 = kk * 32 + ((lane >> 4) << 3);
        bf16x8 o;
        #pragma unroll
        for (int jj = 0; jj < 8; ++jj) o[jj] = (bf16)src[(size_t)col * Ksrc + koff + k0 + jj];
        *(bf16x8*)&dst[(size_t)gg * 8] = o;
    }
}

__global__ void k_bias(const float* __restrict__ W_ih, const float* __restrict__ b_ih,
                       float* __restrict__ bias_c) {
    const int i = blockIdx.x * blockDim.x + threadIdx.x;
    if (i < 64 * 768) {
        const int c = i / 768, n = i - c * 768;
        bias_c[i] = W_ih[(size_t)n * 96 + 32 + c] + b_ih[n];
    }
}

extern "C" void kernel_launch(void* const* d_in, const int* in_sizes, int n_in,
                              void* d_out, int out_size, void* d_ws, size_t ws_size,
                              hipStream_t stream) {
    const float* x_seq = (const float*)d_in[0];
    const int*   cidx  = (const int*)d_in[1];
    const float* W_ih  = (const float*)d_in[3];
    const float* W_hh  = (const float*)d_in[4];
    const float* b_ih  = (const float*)d_in[5];
    const float* b_n   = (const float*)d_in[6];
    const float* W0    = (const float*)d_in[7];
    const float* b0    = (const float*)d_in[8];
    const float* W1    = (const float*)d_in[9];
    const float* b1    = (const float*)d_in[10];
    const float* W2    = (const float*)d_in[11];
    const float* b2    = (const float*)d_in[12];
    const float* W_dec = (const float*)d_in[13];
    const float* b_dec = (const float*)d_in[14];
    float* out = (float*)d_out;
    const int H = out_size / (B_TOT * NT_OUT);
    char* ws = (char*)d_ws;

    // zero flags + xcd map + grid counter (every launch -> graph-replay safe)
    hipMemsetAsync(ws + WS_FLG, 0, 8192, stream);

    k_pack<<<64, 256, 0, stream>>>(W0, (bf16*)(ws + WS_W0), 512, 256, 256, 0);
    k_pack<<<128, 256, 0, stream>>>(W1, (bf16*)(ws + WS_W1), 512, 512, 512, 0);
    k_pack<<<64, 256, 0, stream>>>(W2, (bf16*)(ws + WS_W2), 256, 512, 512, 0);
    k_pack<<<96, 256, 0, stream>>>(W_hh, (bf16*)(ws + WS_WHH), 768, 256, 256, 0);
    k_pack<<<12, 256, 0, stream>>>(W_ih, (bf16*)(ws + WS_WIH), 768, 32, 96, 0);
    k_bias<<<(64 * 768 + 255) / 256, 256, 0, stream>>>(W_ih, b_ih, (float*)(ws + WS_BC));

    k_main<<<NBLK, NTHR, 0, stream>>>(x_seq, cidx, b_n, b0, b1, b2, W_dec, b_dec,
                                      ws, out, H);
}